// Round 1
// baseline (141.020 us; speedup 1.0000x reference)
//
#include <hip/hip_runtime.h>
#include <hip/hip_bf16.h>

typedef __attribute__((ext_vector_type(8))) short short8;
typedef __attribute__((ext_vector_type(8))) unsigned short ushort8;
typedef __attribute__((ext_vector_type(4))) float floatx4;

#define B_SZ 4
#define N_SZ 1024
#define DIM_SZ 1024
#define H_SZ 16
#define HD_SZ 64
#define M_TOT 4096
#define QK_ELEMS (M_TOT * DIM_SZ)  // 4194304 bf16 elems per tensor (Q, then K)

__device__ __forceinline__ unsigned short f2bf(float x) {
  union { float f; unsigned u; } v; v.f = x;
  unsigned r = v.u + 0x7FFFu + ((v.u >> 16) & 1u);  // round-to-nearest-even
  return (unsigned short)(r >> 16);
}

// ---------------- Phase 1: Q/K projection GEMM (bf16 MFMA) ----------------
// C[m, o] = sum_k H[m,k] * W[o,k]   (both row-major along k: A @ B^T form)
// Output scattered to [b, h, n, d] bf16 layout for the attention phase.
__global__ __launch_bounds__(256) void proj_qk(
    const float* __restrict__ hs,   // [4096][1024]
    const float* __restrict__ Wq,   // [1024][1024]
    const float* __restrict__ Wk,
    unsigned short* __restrict__ qk)  // bf16 bits; Q at 0, K at QK_ELEMS
{
  const int which = blockIdx.z;
  const float* __restrict__ W = which ? Wk : Wq;
  unsigned short* __restrict__ outp = qk + (size_t)which * QK_ELEMS;

  const int tid = threadIdx.x;
  const int lane = tid & 63;
  const int wave = tid >> 6;
  const int mbase = blockIdx.x * 64;
  const int obase = blockIdx.y * 64;

  __shared__ unsigned short As[64][40];  // 64x32 tile, pad to 40 (2-way conflicts only)
  __shared__ unsigned short Bs[64][40];

  floatx4 zero = {0.f, 0.f, 0.f, 0.f};
  floatx4 acc00 = zero, acc01 = zero, acc10 = zero, acc11 = zero;

  const int lr = tid >> 2;        // 0..63: tile row this thread stages
  const int lk = (tid & 3) * 8;   // 0,8,16,24: k-offset (8 elems = 16B bf16)
  const float* aptr = hs + (size_t)(mbase + lr) * DIM_SZ + lk;
  const float* bptr = W + (size_t)(obase + lr) * DIM_SZ + lk;

  const int fr = lane & 15;
  const int k8 = (lane >> 4) * 8;
  const int rb = (wave >> 1) * 32;  // wave's 32-row block
  const int cb = (wave & 1) * 32;   // wave's 32-col block

  for (int k0 = 0; k0 < DIM_SZ; k0 += 32) {
    floatx4 av0 = *reinterpret_cast<const floatx4*>(aptr + k0);
    floatx4 av1 = *reinterpret_cast<const floatx4*>(aptr + k0 + 4);
    floatx4 bv0 = *reinterpret_cast<const floatx4*>(bptr + k0);
    floatx4 bv1 = *reinterpret_cast<const floatx4*>(bptr + k0 + 4);
    ushort8 a8, b8;
#pragma unroll
    for (int j = 0; j < 4; ++j) {
      a8[j] = f2bf(av0[j]); a8[4 + j] = f2bf(av1[j]);
      b8[j] = f2bf(bv0[j]); b8[4 + j] = f2bf(bv1[j]);
    }
    *reinterpret_cast<ushort8*>(&As[lr][lk]) = a8;
    *reinterpret_cast<ushort8*>(&Bs[lr][lk]) = b8;
    __syncthreads();

    short8 a0 = *reinterpret_cast<const short8*>(&As[rb + fr][k8]);
    short8 a1 = *reinterpret_cast<const short8*>(&As[rb + 16 + fr][k8]);
    short8 b0 = *reinterpret_cast<const short8*>(&Bs[cb + fr][k8]);
    short8 b1 = *reinterpret_cast<const short8*>(&Bs[cb + 16 + fr][k8]);
    acc00 = __builtin_amdgcn_mfma_f32_16x16x32_bf16(a0, b0, acc00, 0, 0, 0);
    acc01 = __builtin_amdgcn_mfma_f32_16x16x32_bf16(a0, b1, acc01, 0, 0, 0);
    acc10 = __builtin_amdgcn_mfma_f32_16x16x32_bf16(a1, b0, acc10, 0, 0, 0);
    acc11 = __builtin_amdgcn_mfma_f32_16x16x32_bf16(a1, b1, acc11, 0, 0, 0);
    __syncthreads();
  }

  // C/D layout: col = lane&15, row = (lane>>4)*4 + r  [measured m89]
  const int rrow = (lane >> 4) * 4;
#pragma unroll
  for (int mi = 0; mi < 2; ++mi) {
#pragma unroll
    for (int ni = 0; ni < 2; ++ni) {
      floatx4 a = (mi == 0) ? (ni == 0 ? acc00 : acc01) : (ni == 0 ? acc10 : acc11);
      int o = obase + cb + ni * 16 + fr;
      int h = o >> 6, d = o & 63;
#pragma unroll
      for (int r = 0; r < 4; ++r) {
        int mrow = mbase + rb + mi * 16 + rrow + r;
        int bb = mrow >> 10, n = mrow & 1023;
        outp[((size_t)((bb * H_SZ + h) * N_SZ + n)) * HD_SZ + d] = f2bf(a[r]);
      }
    }
  }
}

// ---------------- Phase 2: scores + softmax + shaped-attention epilogue ----
// One block = 16 query rows of one (b,h). 4 waves x 256 cols each; full
// 1024-wide score row lives in registers (16 x f32x4 per lane).
__global__ __launch_bounds__(256) void attn_out(
    const unsigned short* __restrict__ qk,
    const int* __restrict__ mask,
    const float* __restrict__ g1p,
    const float* __restrict__ g2p,
    const float* __restrict__ g3p,
    float* __restrict__ out)
{
  const int bh = blockIdx.y;       // b*16 + h
  const int b = bh >> 4;
  const int qbase = blockIdx.x * 16;
  const int tid = threadIdx.x;
  const int lane = tid & 63;
  const int wave = tid >> 6;

  __shared__ float nzf[N_SZ];
  __shared__ float wsum[4];
  __shared__ float rowsums[4][16];

  float cnt = 0.f;
  for (int i = tid; i < N_SZ; i += 256) {
    float v = (mask[b * N_SZ + i] == 0) ? 1.0f : 0.0f;
    nzf[i] = v;
    cnt += v;
  }
#pragma unroll
  for (int off = 32; off >= 1; off >>= 1) cnt += __shfl_xor(cnt, off);
  if (lane == 0) wsum[wave] = cnt;
  __syncthreads();
  const float nnz = wsum[0] + wsum[1] + wsum[2] + wsum[3];

  const int fr = lane & 15;
  const int k8 = (lane >> 4) * 8;

  // Q fragment (A operand): row = lane&15, k-chunk = (lane>>4)*8, 2 k-steps
  const unsigned short* qptr =
      qk + ((size_t)(bh * N_SZ + qbase + fr)) * HD_SZ + k8;
  short8 qa0 = *reinterpret_cast<const short8*>(qptr);
  short8 qa1 = *reinterpret_cast<const short8*>(qptr + 32);

  const unsigned short* kbase = qk + (size_t)QK_ELEMS + (size_t)bh * N_SZ * HD_SZ;

  floatx4 zero = {0.f, 0.f, 0.f, 0.f};
  floatx4 acc[16];
#pragma unroll
  for (int c = 0; c < 16; ++c) acc[c] = zero;

#pragma unroll
  for (int c = 0; c < 16; ++c) {
    int col = wave * 256 + c * 16 + fr;  // key index (B-operand col)
    const unsigned short* kp = kbase + (size_t)col * HD_SZ + k8;
    short8 kb0 = *reinterpret_cast<const short8*>(kp);
    short8 kb1 = *reinterpret_cast<const short8*>(kp + 32);
    acc[c] = __builtin_amdgcn_mfma_f32_16x16x32_bf16(qa0, kb0, acc[c], 0, 0, 0);
    acc[c] = __builtin_amdgcn_mfma_f32_16x16x32_bf16(qa1, kb1, acc[c], 0, 0, 0);
  }

  // softmax (logits ~0.04: no max subtraction needed, exp never overflows)
  const float expscale = 0.015625f * 1.44269504f;  // SCALE * log2(e)
  float psum[4] = {0.f, 0.f, 0.f, 0.f};
#pragma unroll
  for (int c = 0; c < 16; ++c) {
#pragma unroll
    for (int r = 0; r < 4; ++r) {
      float p = __builtin_amdgcn_exp2f(acc[c][r] * expscale);
      acc[c][r] = p;
      psum[r] += p;
    }
  }
#pragma unroll
  for (int m = 1; m < 16; m <<= 1) {
#pragma unroll
    for (int r = 0; r < 4; ++r) psum[r] += __shfl_xor(psum[r], m);
  }
  if (fr == 0) {
#pragma unroll
    for (int r = 0; r < 4; ++r) rowsums[wave][(lane >> 4) * 4 + r] = psum[r];
  }
  __syncthreads();

  const float g1 = *g1p, g2 = *g2p, g3 = *g3p;
  const float g3n = g3 / nnz;
  float inv[4], nzq[4];
  int rowg[4];
#pragma unroll
  for (int r = 0; r < 4; ++r) {
    int rloc = (lane >> 4) * 4 + r;
    float rs = rowsums[0][rloc] + rowsums[1][rloc] + rowsums[2][rloc] + rowsums[3][rloc];
    inv[r] = g2 / rs;
    rowg[r] = qbase + rloc;
    nzq[r] = nzf[rowg[r]];
  }
#pragma unroll
  for (int c = 0; c < 16; ++c) {
    int col = wave * 256 + c * 16 + fr;
    float nzc = nzf[col];
#pragma unroll
    for (int r = 0; r < 4; ++r) {
      float v = acc[c][r] * inv[r] - g3n * nzq[r] * nzc;
      if (rowg[r] == col) v += g1 * nzq[r];
      out[((size_t)(bh * N_SZ + rowg[r])) * N_SZ + col] = v;
    }
  }
}

extern "C" void kernel_launch(void* const* d_in, const int* in_sizes, int n_in,
                              void* d_out, int out_size, void* d_ws, size_t ws_size,
                              hipStream_t stream) {
  const float* hs = (const float*)d_in[0];
  const int* mask = (const int*)d_in[1];
  const float* Wq = (const float*)d_in[2];
  const float* Wk = (const float*)d_in[3];
  const float* g1 = (const float*)d_in[4];
  const float* g2 = (const float*)d_in[5];
  const float* g3 = (const float*)d_in[6];
  float* out = (float*)d_out;
  unsigned short* qk = (unsigned short*)d_ws;  // 16 MB: Q,K bf16 [b,h,n,d]

  proj_qk<<<dim3(M_TOT / 64, DIM_SZ / 64, 2), 256, 0, stream>>>(hs, Wq, Wk, qk);
  attn_out<<<dim3(N_SZ / 16, B_SZ * H_SZ), 256, 0, stream>>>(qk, mask, g1, g2, g3, out);
}

// Round 2
// 128.019 us; speedup vs baseline: 1.1016x; 1.1016x over previous
//
#include <hip/hip_runtime.h>
#include <hip/hip_bf16.h>

typedef __attribute__((ext_vector_type(8))) short short8;
typedef __attribute__((ext_vector_type(8))) unsigned short ushort8;
typedef __attribute__((ext_vector_type(4))) float floatx4;

#define B_SZ 4
#define N_SZ 1024
#define DIM_SZ 1024
#define H_SZ 16
#define HD_SZ 64
#define M_TOT 4096          // B*N
#define NOUT 2048           // stacked Q|K output dim
#define HS_ELEMS 4194304    // 4096*1024
#define W_ELEMS  1048576    // 1024*1024
#define CVT_TOT  6291456    // HS + 2*W
#define WB_OFF   HS_ELEMS   // ws elem offset of stacked bf16 weights [2048][1024]
#define CB_OFF   CVT_TOT    // ws elem offset of C = [4096][2048] bf16 (Q cols 0-1023, K 1024-2047)

__device__ __forceinline__ unsigned short f2bf(float x) {
  union { float f; unsigned u; } v; v.f = x;
  unsigned r = v.u + 0x7FFFu + ((v.u >> 16) & 1u);  // round-to-nearest-even
  return (unsigned short)(r >> 16);
}

typedef const __attribute__((address_space(1))) void GASV;
typedef __attribute__((address_space(3))) void LASV;
#define GLL16(g, l) __builtin_amdgcn_global_load_lds((GASV*)(g), (LASV*)(l), 16, 0, 0)

// ---------------- Phase 0: f32 -> bf16 pre-convert (hs, Wq|Wk stacked) -----
__global__ __launch_bounds__(256) void convert_bf16(
    const float* __restrict__ hs, const float* __restrict__ Wq,
    const float* __restrict__ Wk, unsigned short* __restrict__ ws)
{
  size_t i = ((size_t)blockIdx.x * 256 + threadIdx.x) * 8;
  const float* src;
  if (i < HS_ELEMS) src = hs + i;
  else if (i < HS_ELEMS + W_ELEMS) src = Wq + (i - HS_ELEMS);
  else src = Wk + (i - HS_ELEMS - W_ELEMS);
  floatx4 v0 = *reinterpret_cast<const floatx4*>(src);
  floatx4 v1 = *reinterpret_cast<const floatx4*>(src + 4);
  ushort8 o;
#pragma unroll
  for (int j = 0; j < 4; ++j) { o[j] = f2bf(v0[j]); o[4 + j] = f2bf(v1[j]); }
  *reinterpret_cast<ushort8*>(ws + i) = o;  // dst offset == i for all three segments
}

// ---------------- Phase 1: fused Q|K projection GEMM (m97 structure) -------
// C[m][o] = sum_k hsb[m][k] * Wb[o][k];  128x128 tile, BK=32, global_load_lds.
__global__ __launch_bounds__(256) void proj_gemm(
    const unsigned short* __restrict__ ws_ro, unsigned short* __restrict__ Cb)
{
  const unsigned short* hsb = ws_ro;
  const unsigned short* Wb = ws_ro + WB_OFF;
  __shared__ unsigned short As[128 * 32];
  __shared__ unsigned short Bs[128 * 32];
  const int tid = threadIdx.x, lane = tid & 63, wave = tid >> 6;
  const int fr = lane & 15, k8 = (lane >> 4) * 8;
  const int wr = wave >> 1, wc = wave & 1;
  const int mbase = blockIdx.x * 128, obase = blockIdx.y * 128;

  const unsigned short* ag = hsb + (size_t)(mbase + (tid >> 2)) * DIM_SZ + (tid & 3) * 8;
  const unsigned short* bg = Wb + (size_t)(obase + (tid >> 2)) * DIM_SZ + (tid & 3) * 8;
  unsigned short* lA = &As[tid * 8];
  unsigned short* lB = &Bs[tid * 8];

  floatx4 acc[4][4];
#pragma unroll
  for (int m = 0; m < 4; ++m)
#pragma unroll
    for (int n = 0; n < 4; ++n) acc[m][n] = floatx4{0.f, 0.f, 0.f, 0.f};

  for (int k0 = 0; k0 < DIM_SZ; k0 += 32) {
    GLL16(ag + k0, lA);
    GLL16(ag + k0 + 64 * DIM_SZ, lA + 2048);
    GLL16(bg + k0, lB);
    GLL16(bg + k0 + 64 * DIM_SZ, lB + 2048);
    __syncthreads();  // compiler drains vmcnt before s_barrier
    short8 af[4], bfr[4];
#pragma unroll
    for (int m = 0; m < 4; ++m)
      af[m] = *reinterpret_cast<const short8*>(&As[(wr * 64 + m * 16 + fr) * 32 + k8]);
#pragma unroll
    for (int n = 0; n < 4; ++n)
      bfr[n] = *reinterpret_cast<const short8*>(&Bs[(wc * 64 + n * 16 + fr) * 32 + k8]);
#pragma unroll
    for (int m = 0; m < 4; ++m)
#pragma unroll
      for (int n = 0; n < 4; ++n)
        acc[m][n] = __builtin_amdgcn_mfma_f32_16x16x32_bf16(af[m], bfr[n], acc[m][n], 0, 0, 0);
    __syncthreads();
  }

  const int rr = (lane >> 4) * 4;
#pragma unroll
  for (int m = 0; m < 4; ++m)
#pragma unroll
    for (int n = 0; n < 4; ++n) {
      int col = obase + wc * 64 + n * 16 + fr;
#pragma unroll
      for (int r = 0; r < 4; ++r) {
        int row = mbase + wr * 64 + m * 16 + rr + r;
        Cb[(size_t)row * NOUT + col] = f2bf(acc[m][n][r]);
      }
    }
}

// ---------------- Phase 2: scores + softmax + shaped-attention epilogue ----
__global__ __launch_bounds__(256) void attn_out(
    const unsigned short* __restrict__ Cb,   // [4096][2048] bf16: Q | K
    const int* __restrict__ mask,
    const float* __restrict__ g1p,
    const float* __restrict__ g2p,
    const float* __restrict__ g3p,
    float* __restrict__ out)
{
  const int bh = blockIdx.y;       // b*16 + h
  const int b = bh >> 4;
  const int h = bh & 15;
  const int qbase = blockIdx.x * 16;
  const int tid = threadIdx.x;
  const int lane = tid & 63;
  const int wave = tid >> 6;

  __shared__ float nzf[N_SZ];
  __shared__ float wsum[4];
  __shared__ float rowsums[4][16];

  float cnt = 0.f;
  for (int i = tid; i < N_SZ; i += 256) {
    float v = (mask[b * N_SZ + i] == 0) ? 1.0f : 0.0f;
    nzf[i] = v;
    cnt += v;
  }
#pragma unroll
  for (int off = 32; off >= 1; off >>= 1) cnt += __shfl_xor(cnt, off);
  if (lane == 0) wsum[wave] = cnt;
  __syncthreads();
  const float nnz = wsum[0] + wsum[1] + wsum[2] + wsum[3];

  const int fr = lane & 15;
  const int k8 = (lane >> 4) * 8;

  // Q fragment (A operand): row = qbase+fr, k-chunk = (lane>>4)*8 within d=64
  const unsigned short* qptr =
      Cb + (size_t)(b * N_SZ + qbase + fr) * NOUT + h * HD_SZ + k8;
  short8 qa0 = *reinterpret_cast<const short8*>(qptr);
  short8 qa1 = *reinterpret_cast<const short8*>(qptr + 32);

  floatx4 acc[16];
#pragma unroll
  for (int c = 0; c < 16; ++c) acc[c] = floatx4{0.f, 0.f, 0.f, 0.f};

#pragma unroll
  for (int c = 0; c < 16; ++c) {
    int col = wave * 256 + c * 16 + fr;  // key index (B-operand row)
    const unsigned short* kp =
        Cb + (size_t)(b * N_SZ + col) * NOUT + N_SZ + h * HD_SZ + k8;
    short8 kb0 = *reinterpret_cast<const short8*>(kp);
    short8 kb1 = *reinterpret_cast<const short8*>(kp + 32);
    acc[c] = __builtin_amdgcn_mfma_f32_16x16x32_bf16(qa0, kb0, acc[c], 0, 0, 0);
    acc[c] = __builtin_amdgcn_mfma_f32_16x16x32_bf16(qa1, kb1, acc[c], 0, 0, 0);
  }

  // softmax (logits ~0.04 in magnitude: max-subtraction unnecessary)
  const float expscale = 0.015625f * 1.44269504f;  // SCALE * log2(e)
  float psum[4] = {0.f, 0.f, 0.f, 0.f};
#pragma unroll
  for (int c = 0; c < 16; ++c) {
#pragma unroll
    for (int r = 0; r < 4; ++r) {
      float p = __builtin_amdgcn_exp2f(acc[c][r] * expscale);
      acc[c][r] = p;
      psum[r] += p;
    }
  }
#pragma unroll
  for (int m = 1; m < 16; m <<= 1) {
#pragma unroll
    for (int r = 0; r < 4; ++r) psum[r] += __shfl_xor(psum[r], m);
  }
  if (fr == 0) {
#pragma unroll
    for (int r = 0; r < 4; ++r) rowsums[wave][(lane >> 4) * 4 + r] = psum[r];
  }
  __syncthreads();

  const float g1 = *g1p, g2 = *g2p, g3 = *g3p;
  const float g3n = g3 / nnz;
  float inv[4], nzq[4];
  int rowg[4];
#pragma unroll
  for (int r = 0; r < 4; ++r) {
    int rloc = (lane >> 4) * 4 + r;
    float rs = rowsums[0][rloc] + rowsums[1][rloc] + rowsums[2][rloc] + rowsums[3][rloc];
    inv[r] = g2 / rs;
    rowg[r] = qbase + rloc;
    nzq[r] = nzf[rowg[r]];
  }
#pragma unroll
  for (int c = 0; c < 16; ++c) {
    int col = wave * 256 + c * 16 + fr;
    float nzc = nzf[col];
#pragma unroll
    for (int r = 0; r < 4; ++r) {
      float v = acc[c][r] * inv[r] - g3n * nzq[r] * nzc;
      if (rowg[r] == col) v += g1 * nzq[r];
      out[((size_t)(bh * N_SZ + rowg[r])) * N_SZ + col] = v;
    }
  }
}

extern "C" void kernel_launch(void* const* d_in, const int* in_sizes, int n_in,
                              void* d_out, int out_size, void* d_ws, size_t ws_size,
                              hipStream_t stream) {
  const float* hs = (const float*)d_in[0];
  const int* mask = (const int*)d_in[1];
  const float* Wq = (const float*)d_in[2];
  const float* Wk = (const float*)d_in[3];
  const float* g1 = (const float*)d_in[4];
  const float* g2 = (const float*)d_in[5];
  const float* g3 = (const float*)d_in[6];
  float* out = (float*)d_out;
  unsigned short* ws = (unsigned short*)d_ws;

  convert_bf16<<<CVT_TOT / (256 * 8), 256, 0, stream>>>(hs, Wq, Wk, ws);
  proj_gemm<<<dim3(M_TOT / 128, NOUT / 128), 256, 0, stream>>>(ws, ws + CB_OFF);
  attn_out<<<dim3(N_SZ / 16, B_SZ * H_SZ), 256, 0, stream>>>(
      ws + CB_OFF, mask, g1, g2, g3, out);
}